// Round 1
// baseline (837.530 us; speedup 1.0000x reference)
//
#include <hip/hip_runtime.h>
#include <hip/hip_bf16.h>

typedef __bf16 bf16x8 __attribute__((ext_vector_type(8)));
typedef __bf16 bf16x4 __attribute__((ext_vector_type(4)));
typedef float floatx4 __attribute__((ext_vector_type(4)));

static constexpr int BB = 8;      // batch
static constexpr int NN = 1024;   // nodes
static constexpr int FF = 128;    // features
static constexpr int NT = 12;     // attention tasks: 0-5 rel, 6-8 fwd, 9-11 bwd

// workspace layout (bytes)
static constexpr size_t H_OFF  = 0;                                   // f32 [8][12][1024][128]
static constexpr size_t H_SZ   = (size_t)BB*NT*NN*FF*4;
static constexpr size_t EL_OFF = H_OFF + H_SZ;                        // f32 [8][12][1024]
static constexpr size_t EL_SZ  = (size_t)BB*NT*NN*4;
static constexpr size_t ER_OFF = EL_OFF + EL_SZ;                      // f32 [8][12][1024]
static constexpr size_t S_OFF  = ER_OFF + EL_SZ;                      // f32 [8][12][128]
static constexpr size_t S_SZ   = (size_t)BB*NT*FF*4;
static constexpr size_t DV_OFF = S_OFF + S_SZ;                        // f32 [8][3][1024]

// ---------------------------------------------------------------------------
// K1: bf16 MFMA GEMM. C[8192 x 1664] = X[8192 x 128] @ Wcat^T, + bias.
// col channel 0 -> d_out init (self term); channels 1..12 -> H[b][ch-1][n][f].
// Tile 64(M) x 64(N), K=128 resident. 4 waves, each wave 16 rows x 64 cols.
// ---------------------------------------------------------------------------
__global__ __launch_bounds__(256) void k1_gemm(
    const float* __restrict__ x,
    const float* __restrict__ fc_w, const float* __restrict__ fc_b,
    const float* __restrict__ fwd_fc_w, const float* __restrict__ fwd_fc_b,
    const float* __restrict__ bwd_fc_w, const float* __restrict__ bwd_fc_b,
    const float* __restrict__ self_w, const float* __restrict__ self_b,
    const float* __restrict__ bias_in,
    float* __restrict__ out, float* __restrict__ H)
{
    __shared__ __align__(16) __bf16 Als[64 * 136];  // [row][k], +8 bf16 pad
    __shared__ __align__(16) __bf16 Bls[64 * 136];  // [col-f][k], +8 pad

    const int tid = threadIdx.x;
    const int m0 = blockIdx.y * 64;       // global row (b*1024+n)
    const int n0 = blockIdx.x * 64;       // global col (ch*128+f)
    const int ch = n0 >> 7;               // tile spans exactly half a channel
    const int f0 = n0 & 127;              // 0 or 64

    const float* wsel; const float* bsel;
    if (ch == 0)      { wsel = self_w;                    bsel = self_b; }
    else if (ch <= 6) { wsel = fc_w     + (ch-1)*16384;   bsel = fc_b     + (ch-1)*128; }
    else if (ch <= 9) { wsel = fwd_fc_w + (ch-7)*16384;   bsel = fwd_fc_b + (ch-7)*128; }
    else              { wsel = bwd_fc_w + (ch-10)*16384;  bsel = bwd_fc_b + (ch-10)*128; }

    // stage A (x rows, fp32 -> bf16) and B (w rows [f][k], fp32 -> bf16)
    for (int it = 0; it < 8; ++it) {
        int idx = tid + it * 256;           // 0..2047 float4 slots
        int r  = idx >> 5;                  // local row 0..63
        int c4 = idx & 31;                  // float4 index within 128-K row
        float4 va = *reinterpret_cast<const float4*>(x + (size_t)(m0 + r) * 128 + c4 * 4);
        *reinterpret_cast<bf16x4*>(&Als[r * 136 + c4 * 4]) =
            (bf16x4){(__bf16)va.x, (__bf16)va.y, (__bf16)va.z, (__bf16)va.w};
        float4 vb = *reinterpret_cast<const float4*>(wsel + (size_t)(f0 + r) * 128 + c4 * 4);
        *reinterpret_cast<bf16x4*>(&Bls[r * 136 + c4 * 4]) =
            (bf16x4){(__bf16)vb.x, (__bf16)vb.y, (__bf16)vb.z, (__bf16)vb.w};
    }
    __syncthreads();

    const int wid  = tid >> 6;
    const int lane = tid & 63;
    const int lrow = lane & 15;
    const int quad = lane >> 4;

    floatx4 acc[4];
    #pragma unroll
    for (int c = 0; c < 4; ++c) acc[c] = (floatx4){0.f, 0.f, 0.f, 0.f};

    #pragma unroll
    for (int kk = 0; kk < 4; ++kk) {
        const int k0 = kk * 32 + quad * 8;
        bf16x8 afr = *reinterpret_cast<const bf16x8*>(&Als[(wid * 16 + lrow) * 136 + k0]);
        #pragma unroll
        for (int c = 0; c < 4; ++c) {
            bf16x8 bfr = *reinterpret_cast<const bf16x8*>(&Bls[(c * 16 + lrow) * 136 + k0]);
            acc[c] = __builtin_amdgcn_mfma_f32_16x16x32_bf16(afr, bfr, acc[c], 0, 0, 0);
        }
    }

    // epilogue: D[row=(quad*4+r)][col=lane&15]  (verified m89/m91 layout)
    #pragma unroll
    for (int c = 0; c < 4; ++c) {
        int fcol = f0 + c * 16 + lrow;
        float bv = bsel[fcol];
        if (ch == 0) bv += bias_in[fcol];
        #pragma unroll
        for (int r = 0; r < 4; ++r) {
            int m = m0 + wid * 16 + quad * 4 + r;
            float val = acc[c][r] + bv;
            if (ch == 0) {
                out[(size_t)m * 128 + fcol] = val;
            } else {
                H[((size_t)(m >> 10) * NT + (ch - 1)) * ((size_t)NN * FF)
                  + (size_t)(m & 1023) * 128 + fcol] = val;
            }
        }
    }
}

// ---------------------------------------------------------------------------
// K2: el/er per (b, task, row). Wave per row; fold att bias into er.
// ---------------------------------------------------------------------------
__global__ __launch_bounds__(256) void k2_elre(
    const float* __restrict__ H,
    const float* __restrict__ att_w, const float* __restrict__ att_b,
    const float* __restrict__ fwd_att_w, const float* __restrict__ fwd_att_b,
    const float* __restrict__ bwd_att_w, const float* __restrict__ bwd_att_b,
    float* __restrict__ el, float* __restrict__ er)
{
    const int gw   = blockIdx.x * 4 + (threadIdx.x >> 6);
    const int lane = threadIdx.x & 63;
    const int b    = gw / (NT * NN);
    const int rem  = gw % (NT * NN);
    const int t    = rem >> 10;
    const int n    = rem & 1023;

    const float* w; float bb;
    if (t < 6)      { w = att_w     + t * 256;       bb = att_b[t]; }
    else if (t < 9) { w = fwd_att_w + (t - 6) * 256; bb = fwd_att_b[t - 6]; }
    else            { w = bwd_att_w + (t - 9) * 256; bb = bwd_att_b[t - 9]; }
    const int hch = (t < 6) ? t : 5;   // tasks 6..11 use stale h5

    const float* hr = H + ((size_t)b * NT + hch) * ((size_t)NN * FF) + (size_t)n * 128;
    float h0 = hr[lane], h1 = hr[lane + 64];
    float pe = h0 * w[lane]       + h1 * w[lane + 64];
    float pr = h0 * w[128 + lane] + h1 * w[128 + lane + 64];
    #pragma unroll
    for (int off = 32; off; off >>= 1) {
        pe += __shfl_xor(pe, off);
        pr += __shfl_xor(pr, off);
    }
    if (lane == 0) {
        el[(size_t)(b * NT + t) * NN + n] = pe;
        er[(size_t)(b * NT + t) * NN + n] = pr + bb;
    }
}

// ---------------------------------------------------------------------------
// K3: column sums S[b][t][f] = sum_n H[b][t][n][f]
// ---------------------------------------------------------------------------
__global__ __launch_bounds__(512) void k3_ssum(const float* __restrict__ H,
                                               float* __restrict__ S)
{
    __shared__ float red[512];
    const int bt = blockIdx.x;                 // b*12+t, 0..95
    const int f  = threadIdx.x & 127;
    const int q  = threadIdx.x >> 7;
    const float* base = H + (size_t)bt * ((size_t)NN * FF);
    float s = 0.f;
    for (int n = q * 256; n < q * 256 + 256; ++n) s += base[(size_t)n * 128 + f];
    red[threadIdx.x] = s;
    __syncthreads();
    if (q == 0) S[(size_t)bt * 128 + f] = red[f] + red[f + 128] + red[f + 256] + red[f + 384];
}

// ---------------------------------------------------------------------------
// K4: diagonal extract for relations 3..5
// ---------------------------------------------------------------------------
__global__ __launch_bounds__(256) void k4_diag(const float* __restrict__ adjs,
                                               float* __restrict__ dv)
{
    const int gid = blockIdx.x * 256 + threadIdx.x;   // 0..24575 = (b*3+jj)*1024+n
    const int b   = gid / 3072;
    const int rem = gid % 3072;
    const int jj  = rem >> 10;
    const int n   = rem & 1023;
    dv[gid] = adjs[(((size_t)b * 9 + 3 + jj) * NN + n) * NN + n];
}

// ---------------------------------------------------------------------------
// K5: online-softmax edge scan. Wave per (b, task, row). Non-edge class folded
// analytically via column-sum S. atomicAdd contribution into d_out.
// ---------------------------------------------------------------------------
__global__ __launch_bounds__(256) void k5_scan(
    const float* __restrict__ adjs, const float* __restrict__ H,
    const float* __restrict__ el, const float* __restrict__ er,
    const float* __restrict__ S, const float* __restrict__ dv,
    float* __restrict__ out)
{
    const int lane = threadIdx.x & 63;
    const int gw   = blockIdx.x * 4 + (threadIdx.x >> 6);
    const int b    = gw / (NT * NN);
    const int rem  = gw % (NT * NN);
    const int t    = rem >> 10;
    const int i    = rem & 1023;

    const float scale = (t >= 6) ? 0.5f : 1.0f;
    const float* Sp = S + (size_t)(b * NT + t) * 128;
    float* orow = out + ((size_t)b * NN + i) * 128;

    if (t >= 3 && t < 6) {
        // relations 3-5: adjacency = outer(d,d); d_i==0 row -> uniform softmax
        float di = dv[(size_t)(b * 3 + (t - 3)) * NN + i];
        if (!(di > 0.f)) {
            atomicAdd(&orow[lane],      Sp[lane]      * (1.0f / 1024.f));
            atomicAdd(&orow[lane + 64], Sp[lane + 64] * (1.0f / 1024.f));
            return;
        }
    }

    const float eli = el[(size_t)(b * NT + t) * NN + i];
    const float* erp = er + (size_t)(b * NT + t) * NN;
    const float* hb  = H + ((size_t)b * NT + t) * ((size_t)NN * FF);

    const float* arow = nullptr;
    bool col = false;
    const float* cbase = nullptr;
    if (t < 3)       arow = adjs + (((size_t)b * 9 + t) * NN + i) * NN;
    else if (t < 6)  arow = dv + (size_t)(b * 3 + (t - 3)) * NN;   // row = d vector
    else if (t < 9)  arow = adjs + (((size_t)b * 9 + t) * NN + i) * NN;
    else { col = true; cbase = adjs + ((size_t)b * 9 + (t - 3)) * NN * NN + i; }

    float m = -1e30f, l = 0.f, acc0 = 0.f, acc1 = 0.f, s0 = 0.f, s1 = 0.f;
    int deg = 0;

    for (int c = 0; c < 16; ++c) {
        int j = c * 64 + lane;
        float av  = col ? cbase[(size_t)j * NN] : arow[j];
        float erl = erp[j];                       // preload; broadcast via shfl
        unsigned long long mask = __ballot(av > 0.f);
        while (mask) {
            int bit = __ffsll(mask) - 1;
            mask &= (mask - 1);
            int js = c * 64 + bit;
            float e  = eli + __shfl(erl, bit);
            float v  = (e >= 0.f) ? e : 0.01f * e;      // leaky_relu
            float mn = fmaxf(m, v);
            float al = __expf(m - mn);
            float p  = __expf(v - mn);
            const float* hr = hb + (size_t)js * 128;
            float h0 = hr[lane], h1 = hr[lane + 64];
            acc0 = acc0 * al + p * h0;
            acc1 = acc1 * al + p * h1;
            s0 += h0; s1 += h1;
            l = l * al + p;
            m = mn;
            ++deg;
        }
    }

    // fold the (1024-deg) non-edges: value 0 each, h-mass = S - edge-sum
    float mn = fmaxf(m, 0.f);
    float al = __expf(m - mn);
    float p0 = __expf(0.f - mn);
    l = l * al + (float)(1024 - deg) * p0;
    acc0 = acc0 * al + p0 * (Sp[lane]      - s0);
    acc1 = acc1 * al + p0 * (Sp[lane + 64] - s1);

    float inv = scale / l;
    atomicAdd(&orow[lane],      acc0 * inv);
    atomicAdd(&orow[lane + 64], acc1 * inv);
}

// ---------------------------------------------------------------------------
// K6: relu in place
// ---------------------------------------------------------------------------
__global__ __launch_bounds__(256) void k6_relu(float* __restrict__ out)
{
    const int gid = blockIdx.x * 256 + threadIdx.x;
    out[gid] = fmaxf(out[gid], 0.f);
}

extern "C" void kernel_launch(void* const* d_in, const int* in_sizes, int n_in,
                              void* d_out, int out_size, void* d_ws, size_t ws_size,
                              hipStream_t stream)
{
    const float* x         = (const float*)d_in[0];
    const float* adjs      = (const float*)d_in[1];
    const float* fc_w      = (const float*)d_in[2];
    const float* fc_b      = (const float*)d_in[3];
    const float* att_w     = (const float*)d_in[4];
    const float* att_b     = (const float*)d_in[5];
    const float* fwd_fc_w  = (const float*)d_in[6];
    const float* fwd_fc_b  = (const float*)d_in[7];
    const float* fwd_att_w = (const float*)d_in[8];
    const float* fwd_att_b = (const float*)d_in[9];
    const float* bwd_fc_w  = (const float*)d_in[10];
    const float* bwd_fc_b  = (const float*)d_in[11];
    const float* bwd_att_w = (const float*)d_in[12];
    const float* bwd_att_b = (const float*)d_in[13];
    const float* self_w    = (const float*)d_in[14];
    const float* self_b    = (const float*)d_in[15];
    const float* bias_in   = (const float*)d_in[16];
    float* out = (float*)d_out;

    char* ws = (char*)d_ws;
    float* H  = (float*)(ws + H_OFF);
    float* el = (float*)(ws + EL_OFF);
    float* er = (float*)(ws + ER_OFF);
    float* S  = (float*)(ws + S_OFF);
    float* dv = (float*)(ws + DV_OFF);

    // K1: 13-channel projection GEMM (ch0 -> d_out init, 1..12 -> H)
    k1_gemm<<<dim3(26, 128), 256, 0, stream>>>(
        x, fc_w, fc_b, fwd_fc_w, fwd_fc_b, bwd_fc_w, bwd_fc_b,
        self_w, self_b, bias_in, out, H);

    // K2: el/er vectors (8*12*1024 rows, wave per row)
    k2_elre<<<(BB * NT * NN) / 4, 256, 0, stream>>>(
        H, att_w, att_b, fwd_att_w, fwd_att_b, bwd_att_w, bwd_att_b, el, er);

    // K3: column sums
    k3_ssum<<<BB * NT, 512, 0, stream>>>(H, S);

    // K4: diagonals for relations 3..5
    k4_diag<<<(BB * 3 * NN) / 256, 256, 0, stream>>>(adjs, dv);

    // K5: edge scans + accumulation
    k5_scan<<<(BB * NT * NN) / 4, 256, 0, stream>>>(adjs, H, el, er, S, dv, out);

    // K6: relu
    k6_relu<<<out_size / 256, 256, 0, stream>>>(out);
}

// Round 3
// 765.213 us; speedup vs baseline: 1.0945x; 1.0945x over previous
//
#include <hip/hip_runtime.h>
#include <hip/hip_bf16.h>

typedef __bf16 bf16x8 __attribute__((ext_vector_type(8)));
typedef __bf16 bf16x4 __attribute__((ext_vector_type(4)));
typedef float floatx4 __attribute__((ext_vector_type(4)));

static constexpr int BB = 8;      // batch
static constexpr int NN = 1024;   // nodes
static constexpr int FF = 128;    // features
static constexpr int NT = 12;     // attention tasks: 0-5 rel, 6-8 fwd, 9-11 bwd

// workspace layout (bytes). H is bf16 (halves all H traffic).
static constexpr size_t H_OFF  = 0;                                   // bf16 [8][12][1024][128]
static constexpr size_t H_SZ   = (size_t)BB*NT*NN*FF*2;
static constexpr size_t EL_OFF = H_OFF + H_SZ;                        // f32 [8][12][1024]
static constexpr size_t EL_SZ  = (size_t)BB*NT*NN*4;
static constexpr size_t ER_OFF = EL_OFF + EL_SZ;                      // f32 [8][12][1024]
static constexpr size_t S_OFF  = ER_OFF + EL_SZ;                      // f32 [8][12][128]
static constexpr size_t S_SZ   = (size_t)BB*NT*FF*4;
static constexpr size_t DV_OFF = S_OFF + S_SZ;                        // f32 [8][3][1024]

__device__ __forceinline__ float bf2f(unsigned int u16) {
    union { unsigned int i; float f; } c; c.i = u16 << 16; return c.f;
}
__device__ __forceinline__ unsigned short f2bf(float f) {
    union { float f; unsigned int i; } c; c.f = f;
    unsigned int r = (c.i + 0x7fffu + ((c.i >> 16) & 1u)) >> 16;   // RNE, finite inputs
    return (unsigned short)r;
}

// ---------------------------------------------------------------------------
// K1: bf16 MFMA GEMM. C[8192 x 1664] = X[8192 x 128] @ Wcat^T, + bias.
// col channel 0 -> d_out init (self term, fp32); channels 1..12 -> H (bf16).
// ---------------------------------------------------------------------------
__global__ __launch_bounds__(256) void k1_gemm(
    const float* __restrict__ x,
    const float* __restrict__ fc_w, const float* __restrict__ fc_b,
    const float* __restrict__ fwd_fc_w, const float* __restrict__ fwd_fc_b,
    const float* __restrict__ bwd_fc_w, const float* __restrict__ bwd_fc_b,
    const float* __restrict__ self_w, const float* __restrict__ self_b,
    const float* __restrict__ bias_in,
    float* __restrict__ out, unsigned short* __restrict__ H16)
{
    __shared__ __align__(16) __bf16 Als[64 * 136];  // [row][k], +8 bf16 pad
    __shared__ __align__(16) __bf16 Bls[64 * 136];  // [col-f][k], +8 pad

    const int tid = threadIdx.x;
    const int m0 = blockIdx.y * 64;       // global row (b*1024+n)
    const int n0 = blockIdx.x * 64;       // global col (ch*128+f)
    const int ch = n0 >> 7;               // tile spans exactly half a channel
    const int f0 = n0 & 127;              // 0 or 64

    const float* wsel; const float* bsel;
    if (ch == 0)      { wsel = self_w;                    bsel = self_b; }
    else if (ch <= 6) { wsel = fc_w     + (ch-1)*16384;   bsel = fc_b     + (ch-1)*128; }
    else if (ch <= 9) { wsel = fwd_fc_w + (ch-7)*16384;   bsel = fwd_fc_b + (ch-7)*128; }
    else              { wsel = bwd_fc_w + (ch-10)*16384;  bsel = bwd_fc_b + (ch-10)*128; }

    for (int it = 0; it < 8; ++it) {
        int idx = tid + it * 256;           // 0..2047 float4 slots
        int r  = idx >> 5;                  // local row 0..63
        int c4 = idx & 31;                  // float4 index within 128-K row
        float4 va = *reinterpret_cast<const float4*>(x + (size_t)(m0 + r) * 128 + c4 * 4);
        *reinterpret_cast<bf16x4*>(&Als[r * 136 + c4 * 4]) =
            (bf16x4){(__bf16)va.x, (__bf16)va.y, (__bf16)va.z, (__bf16)va.w};
        float4 vb = *reinterpret_cast<const float4*>(wsel + (size_t)(f0 + r) * 128 + c4 * 4);
        *reinterpret_cast<bf16x4*>(&Bls[r * 136 + c4 * 4]) =
            (bf16x4){(__bf16)vb.x, (__bf16)vb.y, (__bf16)vb.z, (__bf16)vb.w};
    }
    __syncthreads();

    const int wid  = tid >> 6;
    const int lane = tid & 63;
    const int lrow = lane & 15;
    const int quad = lane >> 4;

    floatx4 acc[4];
    #pragma unroll
    for (int c = 0; c < 4; ++c) acc[c] = (floatx4){0.f, 0.f, 0.f, 0.f};

    #pragma unroll
    for (int kk = 0; kk < 4; ++kk) {
        const int k0 = kk * 32 + quad * 8;
        bf16x8 afr = *reinterpret_cast<const bf16x8*>(&Als[(wid * 16 + lrow) * 136 + k0]);
        #pragma unroll
        for (int c = 0; c < 4; ++c) {
            bf16x8 bfr = *reinterpret_cast<const bf16x8*>(&Bls[(c * 16 + lrow) * 136 + k0]);
            acc[c] = __builtin_amdgcn_mfma_f32_16x16x32_bf16(afr, bfr, acc[c], 0, 0, 0);
        }
    }

    // epilogue: D[row=(quad*4+r)][col=lane&15]  (verified m89/m91 layout)
    #pragma unroll
    for (int c = 0; c < 4; ++c) {
        int fcol = f0 + c * 16 + lrow;
        float bv = bsel[fcol];
        if (ch == 0) bv += bias_in[fcol];
        #pragma unroll
        for (int r = 0; r < 4; ++r) {
            int m = m0 + wid * 16 + quad * 4 + r;
            float val = acc[c][r] + bv;
            if (ch == 0) {
                out[(size_t)m * 128 + fcol] = val;
            } else {
                H16[((size_t)(m >> 10) * NT + (ch - 1)) * ((size_t)NN * FF)
                    + (size_t)(m & 1023) * 128 + fcol] = f2bf(val);
            }
        }
    }
}

// ---------------------------------------------------------------------------
// K23: fused el/er matvecs + column sums. One block per (b,t).
// el/er read channel hch (stale h5 for t>=6); column sums MUST read channel t
// (fh/bh for t>=6) — that operand mismatch was the R2 bug.
// ---------------------------------------------------------------------------
__global__ __launch_bounds__(512) void k23(
    const unsigned short* __restrict__ H16,
    const float* __restrict__ att_w, const float* __restrict__ att_b,
    const float* __restrict__ fwd_att_w, const float* __restrict__ fwd_att_b,
    const float* __restrict__ bwd_att_w, const float* __restrict__ bwd_att_b,
    float* __restrict__ el, float* __restrict__ er, float* __restrict__ S)
{
    __shared__ float sred[8][128];
    const int bt   = blockIdx.x;           // b*12+t
    const int b    = bt / 12;
    const int t    = bt % 12;
    const int wid  = threadIdx.x >> 6;
    const int lane = threadIdx.x & 63;
    const int hch  = (t < 6) ? t : 5;      // tasks 6..11 use stale h5 for attention

    const float* w; float bb;
    if (t < 6)      { w = att_w     + t * 256;       bb = att_b[t]; }
    else if (t < 9) { w = fwd_att_w + (t - 6) * 256; bb = fwd_att_b[t - 6]; }
    else            { w = bwd_att_w + (t - 9) * 256; bb = bwd_att_b[t - 9]; }

    const float w0l = w[2 * lane], w1l = w[2 * lane + 1];
    const float w0r = w[128 + 2 * lane], w1r = w[128 + 2 * lane + 1];
    const unsigned short* base_att = H16 + ((size_t)b * NT + hch) * ((size_t)NN * FF);
    const unsigned short* base_sum = H16 + ((size_t)b * NT + t)   * ((size_t)NN * FF);

    float sum0 = 0.f, sum1 = 0.f;
    for (int n = wid; n < NN; n += 8) {
        unsigned int ua = *reinterpret_cast<const unsigned int*>(base_att + (size_t)n * 128 + 2 * lane);
        float h0 = bf2f(ua & 0xffffu), h1 = bf2f(ua >> 16);
        unsigned int us = *reinterpret_cast<const unsigned int*>(base_sum + (size_t)n * 128 + 2 * lane);
        sum0 += bf2f(us & 0xffffu); sum1 += bf2f(us >> 16);
        float pe = h0 * w0l + h1 * w1l;
        float pr = h0 * w0r + h1 * w1r;
        #pragma unroll
        for (int off = 32; off; off >>= 1) {
            pe += __shfl_xor(pe, off);
            pr += __shfl_xor(pr, off);
        }
        if (lane == 0) {
            el[(size_t)bt * NN + n] = pe;
            er[(size_t)bt * NN + n] = pr + bb;
        }
    }
    sred[wid][2 * lane]     = sum0;
    sred[wid][2 * lane + 1] = sum1;
    __syncthreads();
    if (threadIdx.x < 128) {
        float s = 0.f;
        #pragma unroll
        for (int q = 0; q < 8; ++q) s += sred[q][threadIdx.x];
        S[(size_t)bt * 128 + threadIdx.x] = s;
    }
}

// ---------------------------------------------------------------------------
// K4: diagonal extract for relations 3..5
// ---------------------------------------------------------------------------
__global__ __launch_bounds__(256) void k4_diag(const float* __restrict__ adjs,
                                               float* __restrict__ dv)
{
    const int gid = blockIdx.x * 256 + threadIdx.x;   // (b*3+jj)*1024+n
    const int b   = gid / 3072;
    const int rem = gid % 3072;
    const int jj  = rem >> 10;
    const int n   = rem & 1023;
    dv[gid] = adjs[(((size_t)b * 9 + 3 + jj) * NN + n) * NN + n];
}

// ---------------------------------------------------------------------------
// K5: two-phase softmax edge scan, wave per (b,task,row).
//  - XCD-affine swizzle: all blocks of one (b,t) share blockIdx%8 so the
//    256KB H block + column-scanned adjacency stay L2-resident per XCD.
//  - Phase A: e-values computed lane-parallel (16/lane), one wave-max.
//  - Gather: no exp in the dependent chain; p broadcast by shfl; one 4B
//    bf16x2 load per lane per edge (lane owns features 2l, 2l+1).
//  - Non-edge class folded analytically via column-sum S (channel t).
// ---------------------------------------------------------------------------
__global__ __launch_bounds__(256) void k5_scan(
    const float* __restrict__ adjs, const unsigned short* __restrict__ H16,
    const float* __restrict__ el, const float* __restrict__ er,
    const float* __restrict__ S, const float* __restrict__ dv,
    float* __restrict__ out)
{
    const int lane = threadIdx.x & 63;
    const int wid  = threadIdx.x >> 6;
    const int bi   = blockIdx.x;
    const int xcd  = bi & 7;
    const int q    = bi >> 3;              // 0..3071
    const int bt   = (q >> 8) * 8 + xcd;   // 0..95, bt%8 == blockIdx%8
    const int b    = bt / 12;
    const int t    = bt % 12;
    const int i    = (q & 255) * 4 + wid;  // row

    const float scale = (t >= 6) ? 0.5f : 1.0f;
    const float* Sp = S + (size_t)bt * 128;
    float* orow = out + ((size_t)b * NN + i) * 128;

    if (t >= 3 && t < 6) {
        // relations 3-5: adjacency = outer(d,d); d_i==0 row -> uniform softmax
        float di = dv[(size_t)(b * 3 + (t - 3)) * NN + i];
        if (!(di > 0.f)) {
            atomicAdd(&orow[2 * lane],     Sp[2 * lane]     * (1.0f / 1024.f));
            atomicAdd(&orow[2 * lane + 1], Sp[2 * lane + 1] * (1.0f / 1024.f));
            return;
        }
    }

    const float eli = el[(size_t)bt * NN + i];
    const float* erp = er + (size_t)bt * NN;
    const unsigned short* hb = H16 + ((size_t)b * NT + t) * ((size_t)NN * FF);

    const float* arow = nullptr;
    bool colscan = false;
    const float* cbase = nullptr;
    if (t < 3)       arow = adjs + (((size_t)b * 9 + t) * NN + i) * NN;
    else if (t < 6)  arow = dv + (size_t)(b * 3 + (t - 3)) * NN;   // row = d vector
    else if (t < 9)  arow = adjs + (((size_t)b * 9 + t) * NN + i) * NN;
    else { colscan = true; cbase = adjs + ((size_t)b * 9 + (t - 3)) * (size_t)NN * NN + i; }

    // ---- phase A: lane-parallel e-values, wave max ----
    float v[16];
    int emask = 0;
    float vmax = -1e30f;
    #pragma unroll
    for (int c = 0; c < 16; ++c) {
        int j = c * 64 + lane;
        float av = colscan ? cbase[(size_t)j * NN] : arow[j];
        float e  = eli + erp[j];
        float lv = (e >= 0.f) ? e : 0.01f * e;        // leaky_relu
        bool  ed = av > 0.f;
        v[c] = ed ? lv : -1e30f;
        if (ed) { emask |= (1 << c); vmax = fmaxf(vmax, lv); }
    }
    #pragma unroll
    for (int off = 32; off; off >>= 1) vmax = fmaxf(vmax, __shfl_xor(vmax, off));
    const float m = fmaxf(vmax, 0.f);                 // non-edge class value is 0

    // ---- phase B/C: p per lane-edge, gather with shfl broadcast ----
    float lloc = 0.f, acc0 = 0.f, acc1 = 0.f, s0 = 0.f, s1 = 0.f;
    #pragma unroll
    for (int c = 0; c < 16; ++c) {
        bool e = (emask >> c) & 1;
        float p = e ? __expf(v[c] - m) : 0.f;
        lloc += p;
        unsigned long long mk = __ballot(e);
        while (mk) {
            int bit = __ffsll(mk) - 1;
            mk &= mk - 1;
            int js = c * 64 + bit;
            float pj = __shfl(p, bit);
            unsigned int u = *reinterpret_cast<const unsigned int*>(hb + (size_t)js * 128 + 2 * lane);
            float h0 = bf2f(u & 0xffffu), h1 = bf2f(u >> 16);
            acc0 += pj * h0; acc1 += pj * h1;
            s0 += h0; s1 += h1;
        }
    }
    int dg = __popc((unsigned)emask);
    #pragma unroll
    for (int off = 32; off; off >>= 1) {
        lloc += __shfl_xor(lloc, off);
        dg   += __shfl_xor(dg, off);
    }

    // fold the (1024-deg) non-edges: value 0 each, h-mass = S - edge-sum
    float p0 = __expf(-m);
    float l  = lloc + (float)(1024 - dg) * p0;
    acc0 += p0 * (Sp[2 * lane]     - s0);
    acc1 += p0 * (Sp[2 * lane + 1] - s1);

    float inv = scale / l;
    atomicAdd(&orow[2 * lane],     acc0 * inv);
    atomicAdd(&orow[2 * lane + 1], acc1 * inv);
}

// ---------------------------------------------------------------------------
// K6: relu in place
// ---------------------------------------------------------------------------
__global__ __launch_bounds__(256) void k6_relu(float* __restrict__ out)
{
    const int gid = blockIdx.x * 256 + threadIdx.x;
    out[gid] = fmaxf(out[gid], 0.f);
}

extern "C" void kernel_launch(void* const* d_in, const int* in_sizes, int n_in,
                              void* d_out, int out_size, void* d_ws, size_t ws_size,
                              hipStream_t stream)
{
    const float* x         = (const float*)d_in[0];
    const float* adjs      = (const float*)d_in[1];
    const float* fc_w      = (const float*)d_in[2];
    const float* fc_b      = (const float*)d_in[3];
    const float* att_w     = (const float*)d_in[4];
    const float* att_b     = (const float*)d_in[5];
    const float* fwd_fc_w  = (const float*)d_in[6];
    const float* fwd_fc_b  = (const float*)d_in[7];
    const float* fwd_att_w = (const float*)d_in[8];
    const float* fwd_att_b = (const float*)d_in[9];
    const float* bwd_fc_w  = (const float*)d_in[10];
    const float* bwd_fc_b  = (const float*)d_in[11];
    const float* bwd_att_w = (const float*)d_in[12];
    const float* bwd_att_b = (const float*)d_in[13];
    const float* self_w    = (const float*)d_in[14];
    const float* self_b    = (const float*)d_in[15];
    const float* bias_in   = (const float*)d_in[16];
    float* out = (float*)d_out;

    char* ws = (char*)d_ws;
    unsigned short* H16 = (unsigned short*)(ws + H_OFF);
    float* el = (float*)(ws + EL_OFF);
    float* er = (float*)(ws + ER_OFF);
    float* S  = (float*)(ws + S_OFF);
    float* dv = (float*)(ws + DV_OFF);

    // K1: 13-channel projection GEMM (ch0 -> d_out init, 1..12 -> H bf16)
    k1_gemm<<<dim3(26, 128), 256, 0, stream>>>(
        x, fc_w, fc_b, fwd_fc_w, fwd_fc_b, bwd_fc_w, bwd_fc_b,
        self_w, self_b, bias_in, out, H16);

    // K23: fused el/er + column sums, one H pass
    k23<<<BB * NT, 512, 0, stream>>>(
        H16, att_w, att_b, fwd_att_w, fwd_att_b, bwd_att_w, bwd_att_b, el, er, S);

    // K4: diagonals for relations 3..5
    k4_diag<<<(BB * 3 * NN) / 256, 256, 0, stream>>>(adjs, dv);

    // K5: edge scans + accumulation (XCD-affine swizzle)
    k5_scan<<<(BB * NT * NN) / 4, 256, 0, stream>>>(adjs, H16, el, er, S, dv, out);

    // K6: relu
    k6_relu<<<out_size / 256, 256, 0, stream>>>(out);
}

// Round 4
// 559.523 us; speedup vs baseline: 1.4969x; 1.3676x over previous
//
#include <hip/hip_runtime.h>
#include <hip/hip_bf16.h>

typedef __bf16 bf16x8 __attribute__((ext_vector_type(8)));
typedef __bf16 bf16x4 __attribute__((ext_vector_type(4)));
typedef float floatx4 __attribute__((ext_vector_type(4)));

static constexpr int BB = 8;      // batch
static constexpr int NN = 1024;   // nodes
static constexpr int FF = 128;    // features
static constexpr int NT = 12;     // attention tasks: 0-5 rel, 6-8 fwd, 9-11 bwd

// workspace layout (bytes). H is bf16.
static constexpr size_t H_OFF  = 0;                                   // bf16 [8][12][1024][128]
static constexpr size_t H_SZ   = (size_t)BB*NT*NN*FF*2;
static constexpr size_t EL_OFF = H_OFF + H_SZ;                        // f32 [8][12][1024]
static constexpr size_t EL_SZ  = (size_t)BB*NT*NN*4;
static constexpr size_t ER_OFF = EL_OFF + EL_SZ;                      // f32 [8][12][1024]
static constexpr size_t DV_OFF = ER_OFF + EL_SZ;                      // f32 [8][3][1024]

__device__ __forceinline__ float bf2f(unsigned int u16) {
    union { unsigned int i; float f; } c; c.i = u16 << 16; return c.f;
}
__device__ __forceinline__ unsigned short f2bf(float f) {
    union { float f; unsigned int i; } c; c.f = f;
    unsigned int r = (c.i + 0x7fffu + ((c.i >> 16) & 1u)) >> 16;   // RNE, finite inputs
    return (unsigned short)r;
}

// ---------------------------------------------------------------------------
// K1: bf16 MFMA GEMM. C[8192 x 1664] = X[8192 x 128] @ Wcat^T, + bias.
// col channel 0 -> d_out init (self term, fp32); channels 1..12 -> H (bf16).
// ---------------------------------------------------------------------------
__global__ __launch_bounds__(256) void k1_gemm(
    const float* __restrict__ x,
    const float* __restrict__ fc_w, const float* __restrict__ fc_b,
    const float* __restrict__ fwd_fc_w, const float* __restrict__ fwd_fc_b,
    const float* __restrict__ bwd_fc_w, const float* __restrict__ bwd_fc_b,
    const float* __restrict__ self_w, const float* __restrict__ self_b,
    const float* __restrict__ bias_in,
    float* __restrict__ out, unsigned short* __restrict__ H16)
{
    __shared__ __align__(16) __bf16 Als[64 * 136];  // [row][k], +8 bf16 pad
    __shared__ __align__(16) __bf16 Bls[64 * 136];  // [col-f][k], +8 pad

    const int tid = threadIdx.x;
    const int m0 = blockIdx.y * 64;       // global row (b*1024+n)
    const int n0 = blockIdx.x * 64;       // global col (ch*128+f)
    const int ch = n0 >> 7;               // tile spans exactly half a channel
    const int f0 = n0 & 127;              // 0 or 64

    const float* wsel; const float* bsel;
    if (ch == 0)      { wsel = self_w;                    bsel = self_b; }
    else if (ch <= 6) { wsel = fc_w     + (ch-1)*16384;   bsel = fc_b     + (ch-1)*128; }
    else if (ch <= 9) { wsel = fwd_fc_w + (ch-7)*16384;   bsel = fwd_fc_b + (ch-7)*128; }
    else              { wsel = bwd_fc_w + (ch-10)*16384;  bsel = bwd_fc_b + (ch-10)*128; }

    for (int it = 0; it < 8; ++it) {
        int idx = tid + it * 256;           // 0..2047 float4 slots
        int r  = idx >> 5;                  // local row 0..63
        int c4 = idx & 31;                  // float4 index within 128-K row
        float4 va = *reinterpret_cast<const float4*>(x + (size_t)(m0 + r) * 128 + c4 * 4);
        *reinterpret_cast<bf16x4*>(&Als[r * 136 + c4 * 4]) =
            (bf16x4){(__bf16)va.x, (__bf16)va.y, (__bf16)va.z, (__bf16)va.w};
        float4 vb = *reinterpret_cast<const float4*>(wsel + (size_t)(f0 + r) * 128 + c4 * 4);
        *reinterpret_cast<bf16x4*>(&Bls[r * 136 + c4 * 4]) =
            (bf16x4){(__bf16)vb.x, (__bf16)vb.y, (__bf16)vb.z, (__bf16)vb.w};
    }
    __syncthreads();

    const int wid  = tid >> 6;
    const int lane = tid & 63;
    const int lrow = lane & 15;
    const int quad = lane >> 4;

    floatx4 acc[4];
    #pragma unroll
    for (int c = 0; c < 4; ++c) acc[c] = (floatx4){0.f, 0.f, 0.f, 0.f};

    #pragma unroll
    for (int kk = 0; kk < 4; ++kk) {
        const int k0 = kk * 32 + quad * 8;
        bf16x8 afr = *reinterpret_cast<const bf16x8*>(&Als[(wid * 16 + lrow) * 136 + k0]);
        #pragma unroll
        for (int c = 0; c < 4; ++c) {
            bf16x8 bfr = *reinterpret_cast<const bf16x8*>(&Bls[(c * 16 + lrow) * 136 + k0]);
            acc[c] = __builtin_amdgcn_mfma_f32_16x16x32_bf16(afr, bfr, acc[c], 0, 0, 0);
        }
    }

    // epilogue: D[row=(quad*4+r)][col=lane&15]  (verified m89/m91 layout)
    #pragma unroll
    for (int c = 0; c < 4; ++c) {
        int fcol = f0 + c * 16 + lrow;
        float bv = bsel[fcol];
        if (ch == 0) bv += bias_in[fcol];
        #pragma unroll
        for (int r = 0; r < 4; ++r) {
            int m = m0 + wid * 16 + quad * 4 + r;
            float val = acc[c][r] + bv;
            if (ch == 0) {
                out[(size_t)m * 128 + fcol] = val;
            } else {
                H16[((size_t)(m >> 10) * NT + (ch - 1)) * ((size_t)NN * FF)
                    + (size_t)(m & 1023) * 128 + fcol] = f2bf(val);
            }
        }
    }
}

// ---------------------------------------------------------------------------
// K23: el/er matvecs only (S no longer needed). Grid (96,4); wave handles
// 64 rows in groups of 4 so the shuffle-reduction chains overlap (8-wide ILP).
// el/er read channel hch (stale h5 for t>=6).
// ---------------------------------------------------------------------------
__global__ __launch_bounds__(256) void k23(
    const unsigned short* __restrict__ H16,
    const float* __restrict__ att_w, const float* __restrict__ att_b,
    const float* __restrict__ fwd_att_w, const float* __restrict__ fwd_att_b,
    const float* __restrict__ bwd_att_w, const float* __restrict__ bwd_att_b,
    float* __restrict__ el, float* __restrict__ er)
{
    const int bt   = blockIdx.x;           // b*12+t
    const int b    = bt / 12;
    const int t    = bt % 12;
    const int wid  = threadIdx.x >> 6;
    const int lane = threadIdx.x & 63;
    const int hch  = (t < 6) ? t : 5;      // tasks 6..11 use stale h5 for attention
    const int n0   = blockIdx.y * 256 + wid * 64;

    const float* w; float bb;
    if (t < 6)      { w = att_w     + t * 256;       bb = att_b[t]; }
    else if (t < 9) { w = fwd_att_w + (t - 6) * 256; bb = fwd_att_b[t - 6]; }
    else            { w = bwd_att_w + (t - 9) * 256; bb = bwd_att_b[t - 9]; }

    const float w0l = w[2 * lane], w1l = w[2 * lane + 1];
    const float w0r = w[128 + 2 * lane], w1r = w[128 + 2 * lane + 1];
    const unsigned short* base = H16 + ((size_t)b * NT + hch) * ((size_t)NN * FF);

    for (int g = 0; g < 16; ++g) {
        const int n = n0 + g * 4;
        float pe[4], pr[4];
        #pragma unroll
        for (int j = 0; j < 4; ++j) {
            unsigned int u = *reinterpret_cast<const unsigned int*>(
                base + (size_t)(n + j) * 128 + 2 * lane);
            float h0 = bf2f(u & 0xffffu), h1 = bf2f(u >> 16);
            pe[j] = h0 * w0l + h1 * w1l;
            pr[j] = h0 * w0r + h1 * w1r;
        }
        #pragma unroll
        for (int off = 32; off; off >>= 1) {
            #pragma unroll
            for (int j = 0; j < 4; ++j) {
                pe[j] += __shfl_xor(pe[j], off);
                pr[j] += __shfl_xor(pr[j], off);
            }
        }
        if (lane == 0) {
            #pragma unroll
            for (int j = 0; j < 4; ++j) {
                el[(size_t)bt * NN + n + j] = pe[j];
                er[(size_t)bt * NN + n + j] = pr[j] + bb;
            }
        }
    }
}

// ---------------------------------------------------------------------------
// K4: diagonal extract for relations 3..5
// ---------------------------------------------------------------------------
__global__ __launch_bounds__(256) void k4_diag(const float* __restrict__ adjs,
                                               float* __restrict__ dv)
{
    const int gid = blockIdx.x * 256 + threadIdx.x;   // (b*3+jj)*1024+n
    const int b   = gid / 3072;
    const int rem = gid % 3072;
    const int jj  = rem >> 10;
    const int n   = rem & 1023;
    dv[gid] = adjs[(((size_t)b * 9 + 3 + jj) * NN + n) * NN + n];
}

// ---------------------------------------------------------------------------
// K5-dense: flash-style dense attention-apply via MFMA.
//  q_ij = adj ? exp(leaky(el_i+er_j)) : 1  (no max subtraction: |e| ~ O(3));
//  O = Q @ [H | ones]; col 128 of B yields the row-sum l. out += O*scale/l.
//  - batch->XCD affinity (xcd = b), fwd/bwd of the same slab adjacent in time
//  - t=3-5: adjacency synthesized from dv (no slab read)
//  - t=9-11: adjacency tile read row-coalesced, transposed into LDS Q
// ---------------------------------------------------------------------------
static constexpr int KP = 72;   // LDS k-stride in shorts (144B, breaks conflicts)

__global__ __launch_bounds__(256) void k5_dense(
    const float* __restrict__ adjs, const unsigned short* __restrict__ H16,
    const float* __restrict__ el, const float* __restrict__ er,
    const float* __restrict__ dv, float* __restrict__ out)
{
    __shared__ __align__(16) unsigned short Qls[128][KP];  // A: [row][k]
    __shared__ __align__(16) unsigned short Hls[144][KP];  // B: [n][k]; n=128 ones
    __shared__ float lls[128];

    const int tid  = threadIdx.x;
    const int lane = tid & 63;
    const int wv   = tid >> 6;
    const int bi   = blockIdx.x;
    const int b    = bi & 7;               // batch -> XCD
    const int q    = bi >> 3;              // 0..95
    const int tq   = q >> 3;               // 0..11 in schedule order
    // schedule {0,1,2,3,4,5,6,9,7,10,8,11}: fwd/bwd pairs adjacent for L2 reuse
    const int t    = (tq < 6) ? tq : (6 + (tq - 6) / 2 + ((tq - 6) & 1) * 3);
    const int i0   = (q & 7) * 128;
    const int bt   = b * 12 + t;

    const unsigned short* hb = H16 + ((size_t)b * NT + t) * ((size_t)NN * FF);
    const float* elp = el + (size_t)bt * NN;
    const float* erp = er + (size_t)bt * NN;
    const float* dvp = dv + (size_t)(b * 3 + ((t - 3) % 3)) * NN;  // valid when t in 3..5

    // init ones/zero rows of Hls once (n = 128..143)
    for (int idx = tid; idx < 16 * KP; idx += 256) {
        int n = idx / KP, k = idx % KP;
        Hls[128 + n][k] = (n == 0 && k < 64) ? (unsigned short)0x3F80u : (unsigned short)0u;
    }

    floatx4 acc[2][9];
    #pragma unroll
    for (int mt = 0; mt < 2; ++mt)
        #pragma unroll
        for (int nt = 0; nt < 9; ++nt) acc[mt][nt] = (floatx4){0.f, 0.f, 0.f, 0.f};

    int mode; const float* slab = nullptr;
    if (t < 3)       { mode = 0; slab = adjs + ((size_t)b * 9 + t) * (size_t)NN * NN; }
    else if (t < 6)  { mode = 1; }
    else if (t < 9)  { mode = 0; slab = adjs + ((size_t)b * 9 + t) * (size_t)NN * NN; }
    else             { mode = 2; slab = adjs + ((size_t)b * 9 + (t - 3)) * (size_t)NN * NN; }

    const int lrow = lane & 15;
    const int kq   = (lane >> 4) * 8;

    for (int jt = 0; jt < 16; ++jt) {
        const int j0 = jt * 64;
        __syncthreads();   // previous tile's LDS reads complete

        // ---- stage H tile transposed: Hls[f][jj], jj = j-j0 ----
        {
            const int jj = tid >> 2;
            const int fc = (tid & 3) * 32;
            const unsigned short* hrow = hb + (size_t)(j0 + jj) * FF + fc;
            uint4 U0 = *reinterpret_cast<const uint4*>(hrow);
            uint4 U1 = *reinterpret_cast<const uint4*>(hrow + 8);
            uint4 U2 = *reinterpret_cast<const uint4*>(hrow + 16);
            uint4 U3 = *reinterpret_cast<const uint4*>(hrow + 24);
            unsigned int uu[16] = {U0.x,U0.y,U0.z,U0.w, U1.x,U1.y,U1.z,U1.w,
                                   U2.x,U2.y,U2.z,U2.w, U3.x,U3.y,U3.z,U3.w};
            #pragma unroll
            for (int g = 0; g < 16; ++g) {
                Hls[fc + 2 * g][jj]     = (unsigned short)(uu[g] & 0xffffu);
                Hls[fc + 2 * g + 1][jj] = (unsigned short)(uu[g] >> 16);
            }
        }

        // ---- build Q tile ----
        if (mode != 2) {
            const int ri = tid >> 1;
            const int cc = (tid & 1) * 32;
            const float eli = elp[i0 + ri];
            const float di  = (mode == 1) ? dvp[i0 + ri] : 1.f;
            const float* arow = (mode == 0) ? slab + (size_t)(i0 + ri) * NN + j0 + cc
                                            : dvp + j0 + cc;
            const float* erow = erp + j0 + cc;
            #pragma unroll
            for (int g = 0; g < 8; ++g) {
                float4 av = *reinterpret_cast<const float4*>(arow + g * 4);
                float4 ev = *reinterpret_cast<const float4*>(erow + g * 4);
                float qv[4]; float a[4] = {av.x, av.y, av.z, av.w};
                float e4[4] = {ev.x, ev.y, ev.z, ev.w};
                #pragma unroll
                for (int k = 0; k < 4; ++k) {
                    float e  = eli + e4[k];
                    float lv = (e >= 0.f) ? e : 0.01f * e;
                    bool ed  = (a[k] > 0.f) && (di > 0.f);
                    qv[k] = ed ? __expf(lv) : 1.0f;
                }
                unsigned int p0 = (unsigned int)f2bf(qv[0]) | ((unsigned int)f2bf(qv[1]) << 16);
                unsigned int p1 = (unsigned int)f2bf(qv[2]) | ((unsigned int)f2bf(qv[3]) << 16);
                uint2 pk = {p0, p1};
                *reinterpret_cast<uint2*>(&Qls[ri][cc + g * 4]) = pk;
            }
        } else {
            // bwd: Q[ii][jj] = adj[j0+jj][i0+ii]; read adj rows coalesced,
            // write transposed into Qls
            const int jj = tid >> 2;
            const int cc = (tid & 3) * 32;
            const float erj = erp[j0 + jj];
            const float* acol  = slab + (size_t)(j0 + jj) * NN + i0 + cc;
            const float* elrow = elp + i0 + cc;
            #pragma unroll
            for (int g = 0; g < 8; ++g) {
                float4 av = *reinterpret_cast<const float4*>(acol + g * 4);
                float4 lv4 = *reinterpret_cast<const float4*>(elrow + g * 4);
                float a[4] = {av.x, av.y, av.z, av.w};
                float e4[4] = {lv4.x, lv4.y, lv4.z, lv4.w};
                #pragma unroll
                for (int k = 0; k < 4; ++k) {
                    float e  = e4[k] + erj;
                    float lv = (e >= 0.f) ? e : 0.01f * e;
                    float qv = (a[k] > 0.f) ? __expf(lv) : 1.0f;
                    Qls[cc + g * 4 + k][jj] = f2bf(qv);
                }
            }
        }

        __syncthreads();   // tiles staged

        // ---- MFMA: 2 m-tiles x 9 n-tiles x 2 k-halves ----
        #pragma unroll
        for (int kh = 0; kh < 2; ++kh) {
            const int k0 = kh * 32 + kq;
            bf16x8 a0 = *reinterpret_cast<const bf16x8*>(&Qls[wv * 32 + lrow][k0]);
            bf16x8 a1 = *reinterpret_cast<const bf16x8*>(&Qls[wv * 32 + 16 + lrow][k0]);
            #pragma unroll
            for (int nt = 0; nt < 9; ++nt) {
                bf16x8 bfr = *reinterpret_cast<const bf16x8*>(&Hls[nt * 16 + lrow][k0]);
                acc[0][nt] = __builtin_amdgcn_mfma_f32_16x16x32_bf16(a0, bfr, acc[0][nt], 0, 0, 0);
                acc[1][nt] = __builtin_amdgcn_mfma_f32_16x16x32_bf16(a1, bfr, acc[1][nt], 0, 0, 0);
            }
        }
    }

    // ---- epilogue: l from n-tile 8 (col 0), scale, atomic add ----
    const int quad = lane >> 4;
    if (lrow == 0) {
        #pragma unroll
        for (int mt = 0; mt < 2; ++mt)
            #pragma unroll
            for (int r = 0; r < 4; ++r)
                lls[wv * 32 + mt * 16 + quad * 4 + r] = acc[mt][8][r];
    }
    __syncthreads();

    const float scale = (t >= 6) ? 0.5f : 1.0f;
    float* ob = out + ((size_t)b * NN + i0) * FF;
    #pragma unroll
    for (int mt = 0; mt < 2; ++mt) {
        #pragma unroll
        for (int r = 0; r < 4; ++r) {
            const int m = wv * 32 + mt * 16 + quad * 4 + r;
            const float inv = scale / lls[m];
            #pragma unroll
            for (int nt = 0; nt < 8; ++nt)
                atomicAdd(&ob[(size_t)m * FF + nt * 16 + lrow], acc[mt][nt][r] * inv);
        }
    }
}

// ---------------------------------------------------------------------------
// K6: relu in place
// ---------------------------------------------------------------------------
__global__ __launch_bounds__(256) void k6_relu(float* __restrict__ out)
{
    const int gid = blockIdx.x * 256 + threadIdx.x;
    out[gid] = fmaxf(out[gid], 0.f);
}

extern "C" void kernel_launch(void* const* d_in, const int* in_sizes, int n_in,
                              void* d_out, int out_size, void* d_ws, size_t ws_size,
                              hipStream_t stream)
{
    const float* x         = (const float*)d_in[0];
    const float* adjs      = (const float*)d_in[1];
    const float* fc_w      = (const float*)d_in[2];
    const float* fc_b      = (const float*)d_in[3];
    const float* att_w     = (const float*)d_in[4];
    const float* att_b     = (const float*)d_in[5];
    const float* fwd_fc_w  = (const float*)d_in[6];
    const float* fwd_fc_b  = (const float*)d_in[7];
    const float* fwd_att_w = (const float*)d_in[8];
    const float* fwd_att_b = (const float*)d_in[9];
    const float* bwd_fc_w  = (const float*)d_in[10];
    const float* bwd_fc_b  = (const float*)d_in[11];
    const float* bwd_att_w = (const float*)d_in[12];
    const float* bwd_att_b = (const float*)d_in[13];
    const float* self_w    = (const float*)d_in[14];
    const float* self_b    = (const float*)d_in[15];
    const float* bias_in   = (const float*)d_in[16];
    float* out = (float*)d_out;

    char* ws = (char*)d_ws;
    unsigned short* H16 = (unsigned short*)(ws + H_OFF);
    float* el = (float*)(ws + EL_OFF);
    float* er = (float*)(ws + ER_OFF);
    float* dv = (float*)(ws + DV_OFF);

    // K1: 13-channel projection GEMM (ch0 -> d_out init, 1..12 -> H bf16)
    k1_gemm<<<dim3(26, 128), 256, 0, stream>>>(
        x, fc_w, fc_b, fwd_fc_w, fwd_fc_b, bwd_fc_w, bwd_fc_b,
        self_w, self_b, bias_in, out, H16);

    // K23: el/er vectors
    k23<<<dim3(BB * NT, 4), 256, 0, stream>>>(
        H16, att_w, att_b, fwd_att_w, fwd_att_b, bwd_att_w, bwd_att_b, el, er);

    // K4: diagonals for relations 3..5
    k4_diag<<<(BB * 3 * NN) / 256, 256, 0, stream>>>(adjs, dv);

    // K5: dense MFMA attention-apply (96 bt x 8 row-tiles)
    k5_dense<<<BB * NT * 8, 256, 0, stream>>>(adjs, H16, el, er, dv, out);

    // K6: relu
    k6_relu<<<out_size / 256, 256, 0, stream>>>(out);
}